// Round 1
// baseline (382.724 us; speedup 1.0000x reference)
//
#include <hip/hip_runtime.h>

#define NROWS 8192
#define NCOLS 8192
#define LD    8193          // matching_scores row stride (8193x8193 input)
#define NBINS 64
#define KCORR 2048
#define MAXC  8192
#define CAP   192           // candidate bucket capacity per row (mean ~55)
#define RPB   4             // rows per hist block (2048 blocks -> 8 blocks/CU)
// Fast-path cut: v <= exp(m)*1 <= 0.08  =>  cannot exceed t41 (~0.09).
// Bins 0..41 stay bit-exact; crossing expected at n* ~ 33.
#define FCUT_LOG (-2.5257286443082556f)   // ln(0.08)

// inner value EXACTLY as the reference: p = ref_i * src_j; v = exp(m) * p
__device__ __forceinline__ float inner_val(float m, float rr, float sc) {
    float p = rr * sc;
    return expf(m) * p;
}

// Fill outputs with invalid-slot values; zero hist + flags.
__global__ void init_kernel(float* __restrict__ out, unsigned* __restrict__ hist,
                            unsigned* __restrict__ ovfl) {
    int i = blockIdx.x * blockDim.x + threadIdx.x;
    if (i < 2 * MAXC)       out[i] = -1.0f;   // ref/src index fill
    else if (i < 3 * MAXC)  out[i] = 0.0f;    // score fill
    if (i < NBINS) hist[i] = 0u;
    if (i == NBINS) *ovfl = 0u;
}

// Streaming hist. Hot loop rewritten r0: NAMED float4 registers (A/B/C sets)
// with a fully-unrolled 3-deep software pipeline. The previous version staged
// through `float4 buf[2][4]` whose address escaped into lambdas — a rule-#20
// scratch-spill risk that would explain the ~0.7 TB/s effective BW. Named
// scalars cannot be allocaed; loads go straight to VGPRs.
// Slow lanes (~0.7%) only append (col, m-bits) to an LDS bucket. Epilogue
// (once per block): expf + exact t[]-binning of the LDS pairs, global hist
// atomic, coalesced candidate writes.
__global__ __launch_bounds__(256) void hist_kernel(
    const float* __restrict__ ms, const float* __restrict__ refs,
    const float* __restrict__ srcs, unsigned* __restrict__ hist,
    unsigned* __restrict__ candcnt, unsigned* __restrict__ cand_col,
    float* __restrict__ cand_v, unsigned* __restrict__ ovfl, int use_cand)
{
    __shared__ float t[NBINS];
    __shared__ unsigned sub[NBINS];
    __shared__ unsigned cnt[RPB];
    __shared__ uint2 pairs[RPB * CAP];
    int tid = threadIdx.x;
    if (tid == 0) {  // replicate the reference's float32 threshold fold
        float tv = 0.5f;
        for (int n = 0; n < NBINS; ++n) { t[n] = tv; tv = tv - 0.01f; }
    }
    if (tid < NBINS) sub[tid] = 0u;
    if (tid < RPB) cnt[tid] = 0u;
    __syncthreads();

    int r0 = blockIdx.x * RPB;

    auto push = [&](int r, int col, float m) {
        unsigned slot = atomicAdd(&cnt[r], 1u);
        if (slot < CAP)
            pairs[r * CAP + slot] = make_uint2((unsigned)col, __float_as_uint(m));
    };

    // batch b: row = b>>1, half = b&1; float4 index i = h*1024 + k*256 + tid,
    // column = s + 4*i. Only batch (h==1,k==3) can run past nb.
#define ISSUE(b, R0, R1, R2, R3) do {                                          \
        constexpr int r_ = (b) >> 1, h_ = (b) & 1;                             \
        int row_ = r0 + r_;                                                    \
        int s_ = (4 - (row_ & 3)) & 3;  /* (row*8193)%4 == row%4 */            \
        const float4* p4_ = (const float4*)(ms + (size_t)row_ * LD + s_);      \
        int i0_ = h_ * 1024 + tid;                                             \
        R0 = p4_[i0_];                                                         \
        R1 = p4_[i0_ + 256];                                                   \
        R2 = p4_[i0_ + 512];                                                   \
        if (h_ == 1) {                                                         \
            int nb_ = (NCOLS - s_) >> 2;  /* 2048 (s==0) or 2047 */            \
            if (i0_ + 768 < nb_) R3 = p4_[i0_ + 768];                          \
            else R3 = make_float4(-1e30f, -1e30f, -1e30f, -1e30f);             \
        } else {                                                               \
            R3 = p4_[i0_ + 768];                                               \
        }                                                                      \
    } while (0)

#define PROC(r_, c0_, q_) do {                                                 \
        bool a0 = (q_).x > FCUT_LOG, a1 = (q_).y > FCUT_LOG;                   \
        bool a2 = (q_).z > FCUT_LOG, a3 = (q_).w > FCUT_LOG;                   \
        if (a0 | a1 | a2 | a3) {   /* rare (~2.7% of quads) */                 \
            if (a0) push(r_, (c0_) + 0, (q_).x);                               \
            if (a1) push(r_, (c0_) + 1, (q_).y);                               \
            if (a2) push(r_, (c0_) + 2, (q_).z);                               \
            if (a3) push(r_, (c0_) + 3, (q_).w);                               \
        }                                                                      \
    } while (0)

#define CONSUME(b, R0, R1, R2, R3) do {                                        \
        constexpr int r_ = (b) >> 1, h_ = (b) & 1;                             \
        int s_ = (4 - ((r0 + r_) & 3)) & 3;                                    \
        int cb_ = s_ + 4 * (h_ * 1024 + tid);                                  \
        PROC(r_, cb_ + 0,    R0);                                              \
        PROC(r_, cb_ + 1024, R1);                                              \
        PROC(r_, cb_ + 2048, R2);                                              \
        PROC(r_, cb_ + 3072, R3);                                              \
    } while (0)

    float4 A0, A1, A2, A3, B0, B1, B2, B3, C0, C1, C2, C3;
    // 3-deep pipeline: 2 batches (8 dwordx4) in flight at every consume.
    ISSUE(0, A0, A1, A2, A3);
    ISSUE(1, B0, B1, B2, B3);
    ISSUE(2, C0, C1, C2, C3);
    CONSUME(0, A0, A1, A2, A3);
    ISSUE(3, A0, A1, A2, A3);
    CONSUME(1, B0, B1, B2, B3);
    ISSUE(4, B0, B1, B2, B3);
    CONSUME(2, C0, C1, C2, C3);
    ISSUE(5, C0, C1, C2, C3);
    CONSUME(3, A0, A1, A2, A3);
    ISSUE(6, A0, A1, A2, A3);
    CONSUME(4, B0, B1, B2, B3);
    ISSUE(7, B0, B1, B2, B3);
    CONSUME(5, C0, C1, C2, C3);
    CONSUME(6, A0, A1, A2, A3);
    CONSUME(7, B0, B1, B2, B3);

#undef ISSUE
#undef PROC
#undef CONSUME

    // peel/tail pickup: <=4 scalar elements per row, fully parallel
    if (tid < RPB * 8) {
        int r = tid >> 3, e = tid & 7;
        int row = r0 + r;
        int s = (4 - (row & 3)) & 3;
        int nb = (NCOLS - s) >> 2;
        int done = s + 4 * nb;
        int col = -1;
        if (e < s) col = e;
        else if (e - s < NCOLS - done) col = done + (e - s);
        if (col >= 0) {
            float m = ms[(size_t)row * LD + col];
            if (m > FCUT_LOG) push(r, col, m);
        }
    }
    __syncthreads();

    // epilogue: exact binning + candidate emission from LDS pairs
    for (int r = 0; r < RPB; ++r) {
        int row = r0 + r;
        unsigned C = cnt[r];
        unsigned Cc = (C < CAP) ? C : CAP;
        float rr = refs[row];
        for (unsigned i = tid; i < Cc; i += 256) {
            uint2 pr = pairs[r * CAP + i];
            int col = (int)pr.x;
            float m = __uint_as_float(pr.y);
            float v = inner_val(m, rr, srcs[col]);
            int g = (int)floorf((0.5f - v) * 100.0f) + 1;   // guess
            g = (g < 0) ? 0 : ((g > NBINS) ? NBINS : g);
            while (g < NBINS && t[g] >= v) ++g;             // verify (<=1 step)
            while (g > 0 && t[g - 1] < v) --g;
            atomicAdd(&sub[g], 1u);
            if (use_cand) {
                cand_col[(size_t)row * CAP + i] = (unsigned)col;
                cand_v[(size_t)row * CAP + i]   = v;
            }
        }
        if (tid == 0) {
            if (use_cand) candcnt[row] = C;
            if (C > CAP) atomicOr(ovfl, 1u);   // bins unreliable -> full fallback
        }
    }
    __syncthreads();

    if (tid < 64) {   // block-level hist -> global; fast+overflow mass -> bin 63
        unsigned v = sub[tid];
        unsigned p = v;
        #pragma unroll
        for (int off = 1; off < 64; off <<= 1) {
            unsigned u = __shfl_up(p, off);
            if (tid >= off) p += u;
        }
        unsigned binned = __shfl(p, 63);
        unsigned g = (tid == 63) ? (v + (unsigned)(RPB * NCOLS) - binned) : v;
        if (g) atomicAdd(&hist[tid], g);
    }
}

// Threshold selection (exact replay of the while-loop on cumulative bins).
__global__ void mid_kernel(const unsigned* __restrict__ hist,
                           float* __restrict__ thres, unsigned* __restrict__ nstar) {
    int tid = threadIdx.x;
    if (tid < 64) {
        unsigned h = hist[tid];
        unsigned cum = h;
        #pragma unroll
        for (int off = 1; off < 64; off <<= 1) {
            unsigned u = __shfl_up(cum, off);
            if (tid >= off) cum += u;
        }
        unsigned long long mk = __ballot(cum >= (unsigned)KCORR);
        int nsel = mk ? (int)(__ffsll((unsigned long long)mk) - 1) : (NBINS - 1);
        if (tid == 0) {
            float tv = 0.5f;                      // replicate the float fold
            for (int n = 0; n < nsel; ++n) tv = tv - 0.01f;
            *thres = tv;
            *nstar = (unsigned)nsel;
        }
    }
}

// Per-row count. Fast path (candidates valid): one wave per row over <=CAP
// candidate values. Fallback (grid-uniform predicate): 256-thread full scan
// of 4 rows. Merged from the previous rowcnt_kernel + count2_kernel — saves
// one dispatch; bodies are unchanged.
__global__ __launch_bounds__(256) void count_kernel(
    const float* __restrict__ ms, const float* __restrict__ refs,
    const float* __restrict__ srcs, const float* __restrict__ thresp,
    const unsigned* __restrict__ nstar, const unsigned* __restrict__ ovfl,
    const unsigned* __restrict__ candcnt, const float* __restrict__ cand_v,
    unsigned* __restrict__ rowcnt, int use_cand)
{
    __shared__ unsigned tot;
    int ns = (int)*nstar;
    bool fast = (use_cand && ns <= 41 && *ovfl == 0u);   // grid-uniform
    float th = *thresp;

    if (fast) {
        int tid = threadIdx.x, wv = tid >> 6, lane = tid & 63;
        int row = blockIdx.x * 4 + wv;
        unsigned C = candcnt[row];
        unsigned c = 0;
        if (C <= CAP) {
            const float* cv = cand_v + (size_t)row * CAP;
            for (unsigned i = lane; i < C; i += 64)
                c += (cv[i] > th) ? 1u : 0u;
        } else {   // bucket overflow (practically never): full row scan
            float rr = refs[row];
            const float* mrow = ms + (size_t)row * LD;
            for (int col = lane; col < NCOLS; col += 64)
                c += (inner_val(mrow[col], rr, srcs[col]) > th) ? 1u : 0u;
        }
        #pragma unroll
        for (int off = 32; off > 0; off >>= 1) c += __shfl_down(c, off);
        if (lane == 0) rowcnt[row] = c;
        return;
    }

    // full recount fallback (runs only when the candidate path is invalid)
    for (int r4 = 0; r4 < 4; ++r4) {
        int row = blockIdx.x * 4 + r4;
        if (threadIdx.x == 0) tot = 0;
        __syncthreads();
        float rr = refs[row];
        const float* mrow = ms + (size_t)row * LD;
        unsigned c = 0;
        for (int col = threadIdx.x; col < NCOLS; col += 256)
            c += (inner_val(mrow[col], rr, srcs[col]) > th) ? 1u : 0u;
        atomicAdd(&tot, c);
        __syncthreads();
        if (threadIdx.x == 0) rowcnt[row] = tot;
        __syncthreads();
    }
}

// Exclusive prefix over 8192 row counts (single block; always runs).
__global__ __launch_bounds__(1024) void scan_kernel(
    const unsigned* __restrict__ rowcnt, unsigned* __restrict__ rowoff)
{
    __shared__ unsigned ssum[1024];
    int tid = threadIdx.x;
    int r0 = tid * 8;
    unsigned c[8], s = 0;
    #pragma unroll
    for (int k = 0; k < 8; ++k) { c[k] = rowcnt[r0 + k]; s += c[k]; }
    ssum[tid] = s;
    __syncthreads();
    for (int off = 1; off < 1024; off <<= 1) {
        unsigned v = (tid >= off) ? ssum[tid - off] : 0u;
        __syncthreads();
        ssum[tid] += v;
        __syncthreads();
    }
    unsigned excl = ssum[tid] - s;
    #pragma unroll
    for (int k = 0; k < 8; ++k) { rowoff[r0 + k] = excl; excl += c[k]; }
    if (tid == 1023) rowoff[NROWS] = excl;
}

// One wave per row; candidate path touches NO matrix data: filter <=CAP
// candidates by v>th, rank survivors by col (exact row-major order), write.
// Full-scan fallback per row when candidates are unusable.
__global__ __launch_bounds__(256) void cwrite_kernel(
    const float* __restrict__ ms, const float* __restrict__ refs,
    const float* __restrict__ srcs, const float* __restrict__ thresp,
    const unsigned* __restrict__ nstar, const unsigned* __restrict__ ovfl,
    const unsigned* __restrict__ rowoff, const unsigned* __restrict__ candcnt,
    const unsigned* __restrict__ cand_col, const float* __restrict__ cand_v,
    float* __restrict__ out, int use_cand)
{
    __shared__ unsigned s_col[4][64];
    __shared__ float    s_val[4][64];
    int tid = threadIdx.x, wv = tid >> 6, lane = tid & 63;
    int row = blockIdx.x * 4 + wv;
    unsigned base = rowoff[row], next = rowoff[row + 1];
    if (base == next || base >= MAXC) return;   // wave-uniform exit
    float th = *thresp;
    int ns = (int)*nstar;
    unsigned k = next - base;
    bool full = (!use_cand) || (ns >= 42) || (*ovfl != 0u) ||
                (candcnt[row] > CAP) || (k > 64);

    if (!full) {
        unsigned C = candcnt[row];
        const unsigned* cc = cand_col + (size_t)row * CAP;
        const float*    cv = cand_v  + (size_t)row * CAP;
        unsigned nrun = 0;
        for (unsigned c0 = 0; c0 < C; c0 += 64) {
            unsigned i = c0 + lane;
            bool sel = false; unsigned col = 0; float v = 0.f;
            if (i < C) { col = cc[i]; v = cv[i]; sel = (v > th); }
            unsigned long long mk = __ballot(sel);
            if (sel) {
                unsigned idx = nrun + (unsigned)__popcll(mk & ((1ull << lane) - 1ull));
                if (idx < 64) { s_col[wv][idx] = col; s_val[wv][idx] = v; }
            }
            nrun += (unsigned)__popcll(mk);
        }
        __builtin_amdgcn_s_waitcnt(0);       // drain LDS writes
        __builtin_amdgcn_wave_barrier();     // block compiler reordering
        unsigned kk = (nrun < k) ? nrun : k;
        if (kk > 64) kk = 64;
        if (lane < (int)kk) {
            unsigned mycol = s_col[wv][lane];
            float    myval = s_val[wv][lane];
            unsigned rank = 0;
            for (unsigned j = 0; j < kk; ++j)
                rank += (s_col[wv][j] < mycol) ? 1u : 0u;
            unsigned pos = base + rank;
            if (pos < MAXC) {
                out[pos]            = (float)row;
                out[MAXC + pos]     = (float)mycol;
                out[2 * MAXC + pos] = myval;
            }
        }
        return;
    }

    // full-row ordered ballot scan (cold path; correct for any input)
    float rr = refs[row];
    const float* mrow = ms + (size_t)row * LD;
    unsigned running = base;
    for (int c0 = 0; c0 < NCOLS && running < next && running < MAXC; c0 += 64) {
        int col = c0 + lane;
        float v = inner_val(mrow[col], rr, srcs[col]);
        bool pred = v > th;
        unsigned long long mk = __ballot(pred);
        if (pred) {
            unsigned pos = running + (unsigned)__popcll(mk & ((1ull << lane) - 1ull));
            if (pos < MAXC) {
                out[pos]            = (float)row;
                out[MAXC + pos]     = (float)col;
                out[2 * MAXC + pos] = v;
            }
        }
        running += (unsigned)__popcll(mk);
    }
}

extern "C" void kernel_launch(void* const* d_in, const int* in_sizes, int n_in,
                              void* d_out, int out_size, void* d_ws, size_t ws_size,
                              hipStream_t stream) {
    const float* ms  = (const float*)d_in[0];  // 8193x8193
    const float* ref = (const float*)d_in[1];  // 8192
    const float* src = (const float*)d_in[2];  // 8192
    float* out = (float*)d_out;                // [refIdx | srcIdx | scores] as f32

    char* w = (char*)d_ws;
    unsigned* hist   = (unsigned*)(w);                    // 64 u32
    float*    thres  = (float*)(w + 256);
    unsigned* nstar  = (unsigned*)(w + 260);
    unsigned* ovfl   = (unsigned*)(w + 264);
    unsigned* rowcnt = (unsigned*)(w + 512);              // 8192 u32
    unsigned* rowoff = (unsigned*)(w + 512 + NROWS * 4);  // 8193 u32
    size_t cc_off = 512 + (size_t)NROWS * 4 + (size_t)(NROWS + 1) * 4;
    cc_off = (cc_off + 255) & ~(size_t)255;
    unsigned* candcnt  = (unsigned*)(w + cc_off);         // 8192 u32
    size_t col_off = cc_off + (size_t)NROWS * 4;
    unsigned* cand_col = (unsigned*)(w + col_off);        // 8192*CAP u32
    size_t cv_off = col_off + (size_t)NROWS * CAP * 4;
    float* cand_v      = (float*)(w + cv_off);            // 8192*CAP f32
    size_t end_off = cv_off + (size_t)NROWS * CAP * 4;    // ~12.7 MB total

    int use_cand = (ws_size >= end_off) ? 1 : 0;

    init_kernel<<<96, 256, 0, stream>>>(out, hist, ovfl);
    hist_kernel<<<NROWS / RPB, 256, 0, stream>>>(ms, ref, src, hist, candcnt,
                                                 cand_col, cand_v, ovfl, use_cand);
    mid_kernel<<<1, 64, 0, stream>>>(hist, thres, nstar);
    count_kernel<<<NROWS / 4, 256, 0, stream>>>(ms, ref, src, thres, nstar,
                                                ovfl, candcnt, cand_v, rowcnt,
                                                use_cand);
    scan_kernel<<<1, 1024, 0, stream>>>(rowcnt, rowoff);
    cwrite_kernel<<<NROWS / 4, 256, 0, stream>>>(ms, ref, src, thres, nstar,
                                                 ovfl, rowoff, candcnt, cand_col,
                                                 cand_v, out, use_cand);
}

// Round 2
// 380.551 us; speedup vs baseline: 1.0057x; 1.0057x over previous
//
#include <hip/hip_runtime.h>

#define NROWS 8192
#define NCOLS 8192
#define LD    8193          // matching_scores row stride (8193x8193 input)
#define NBINS 64
#define KCORR 2048
#define MAXC  8192
#define CAP   192           // candidate bucket capacity per row (mean ~55)
#define RPB   4             // rows per hist block (2048 blocks -> 8 blocks/CU)
// Fast-path cut: v <= exp(m)*1 <= 0.08  =>  cannot exceed t41 (~0.09).
// Bins 0..41 stay bit-exact; crossing expected at n* ~ 33.
#define FCUT_LOG (-2.5257286443082556f)   // ln(0.08)

// inner value EXACTLY as the reference: p = ref_i * src_j; v = exp(m) * p
__device__ __forceinline__ float inner_val(float m, float rr, float sc) {
    float p = rr * sc;
    return expf(m) * p;
}

// Per-wave threshold recompute (replaces the former mid_kernel dispatch).
// Every wave derives {th, ns} from the global 64-bin hist with the SAME
// float fold as the reference -> bit-identical across all waves/blocks.
// Cost: 1 L2 load/lane + 6 shfl + <=63-step scalar fold (~0.2 us/wave).
__device__ __forceinline__ void wave_thres(const unsigned* __restrict__ hist,
                                           float* th_out, int* ns_out) {
    int lane = threadIdx.x & 63;
    unsigned cum = hist[lane];
    #pragma unroll
    for (int off = 1; off < 64; off <<= 1) {
        unsigned u = __shfl_up(cum, off);
        if (lane >= off) cum += u;
    }
    unsigned long long mk = __ballot(cum >= (unsigned)KCORR);
    int nsel = mk ? (int)(__ffsll((unsigned long long)mk) - 1) : (NBINS - 1);
    float tv = 0.5f;                      // replicate the reference float fold
    for (int n = 0; n < nsel; ++n) tv = tv - 0.01f;
    *th_out = tv;
    *ns_out = nsel;
}

// Fill outputs with invalid-slot values; zero hist + flags.
__global__ void init_kernel(float* __restrict__ out, unsigned* __restrict__ hist,
                            unsigned* __restrict__ ovfl) {
    int i = blockIdx.x * blockDim.x + threadIdx.x;
    if (i < 2 * MAXC)       out[i] = -1.0f;   // ref/src index fill
    else if (i < 3 * MAXC)  out[i] = 0.0f;    // score fill
    if (i < NBINS) hist[i] = 0u;
    if (i == NBINS) *ovfl = 0u;
}

// Streaming hist. Named-register 3-deep software pipeline (8 dwordx4 in
// flight at every consume). Slow lanes (~0.7%) only append (col, m-bits) to
// an LDS bucket. Epilogue (once per block): expf + exact t[]-binning of the
// LDS pairs, global hist atomic, coalesced candidate writes.
// __launch_bounds__(256,2): cap VGPR at 128 so >=2 blocks/CU stay resident.
__global__ __launch_bounds__(256, 2) void hist_kernel(
    const float* __restrict__ ms, const float* __restrict__ refs,
    const float* __restrict__ srcs, unsigned* __restrict__ hist,
    unsigned* __restrict__ candcnt, unsigned* __restrict__ cand_col,
    float* __restrict__ cand_v, unsigned* __restrict__ ovfl, int use_cand)
{
    __shared__ float t[NBINS];
    __shared__ unsigned sub[NBINS];
    __shared__ unsigned cnt[RPB];
    __shared__ uint2 pairs[RPB * CAP];
    int tid = threadIdx.x;
    if (tid == 0) {  // replicate the reference's float32 threshold fold
        float tv = 0.5f;
        for (int n = 0; n < NBINS; ++n) { t[n] = tv; tv = tv - 0.01f; }
    }
    if (tid < NBINS) sub[tid] = 0u;
    if (tid < RPB) cnt[tid] = 0u;
    __syncthreads();

    int r0 = blockIdx.x * RPB;

    auto push = [&](int r, int col, float m) {
        unsigned slot = atomicAdd(&cnt[r], 1u);
        if (slot < CAP)
            pairs[r * CAP + slot] = make_uint2((unsigned)col, __float_as_uint(m));
    };

    // batch b: row = b>>1, half = b&1; float4 index i = h*1024 + k*256 + tid,
    // column = s + 4*i. Only batch (h==1,k==3) can run past nb.
#define ISSUE(b, R0, R1, R2, R3) do {                                          \
        constexpr int r_ = (b) >> 1, h_ = (b) & 1;                             \
        int row_ = r0 + r_;                                                    \
        int s_ = (4 - (row_ & 3)) & 3;  /* (row*8193)%4 == row%4 */            \
        const float4* p4_ = (const float4*)(ms + (size_t)row_ * LD + s_);      \
        int i0_ = h_ * 1024 + tid;                                             \
        R0 = p4_[i0_];                                                         \
        R1 = p4_[i0_ + 256];                                                   \
        R2 = p4_[i0_ + 512];                                                   \
        if (h_ == 1) {                                                         \
            int nb_ = (NCOLS - s_) >> 2;  /* 2048 (s==0) or 2047 */            \
            if (i0_ + 768 < nb_) R3 = p4_[i0_ + 768];                          \
            else R3 = make_float4(-1e30f, -1e30f, -1e30f, -1e30f);             \
        } else {                                                               \
            R3 = p4_[i0_ + 768];                                               \
        }                                                                      \
    } while (0)

#define PROC(r_, c0_, q_) do {                                                 \
        bool a0 = (q_).x > FCUT_LOG, a1 = (q_).y > FCUT_LOG;                   \
        bool a2 = (q_).z > FCUT_LOG, a3 = (q_).w > FCUT_LOG;                   \
        if (a0 | a1 | a2 | a3) {   /* rare (~2.7% of quads) */                 \
            if (a0) push(r_, (c0_) + 0, (q_).x);                               \
            if (a1) push(r_, (c0_) + 1, (q_).y);                               \
            if (a2) push(r_, (c0_) + 2, (q_).z);                               \
            if (a3) push(r_, (c0_) + 3, (q_).w);                               \
        }                                                                      \
    } while (0)

#define CONSUME(b, R0, R1, R2, R3) do {                                        \
        constexpr int r_ = (b) >> 1, h_ = (b) & 1;                             \
        int s_ = (4 - ((r0 + r_) & 3)) & 3;                                    \
        int cb_ = s_ + 4 * (h_ * 1024 + tid);                                  \
        PROC(r_, cb_ + 0,    R0);                                              \
        PROC(r_, cb_ + 1024, R1);                                              \
        PROC(r_, cb_ + 2048, R2);                                              \
        PROC(r_, cb_ + 3072, R3);                                              \
    } while (0)

    float4 A0, A1, A2, A3, B0, B1, B2, B3, C0, C1, C2, C3;
    // 3-deep pipeline: 2 batches (8 dwordx4) in flight at every consume.
    ISSUE(0, A0, A1, A2, A3);
    ISSUE(1, B0, B1, B2, B3);
    ISSUE(2, C0, C1, C2, C3);
    CONSUME(0, A0, A1, A2, A3);
    ISSUE(3, A0, A1, A2, A3);
    CONSUME(1, B0, B1, B2, B3);
    ISSUE(4, B0, B1, B2, B3);
    CONSUME(2, C0, C1, C2, C3);
    ISSUE(5, C0, C1, C2, C3);
    CONSUME(3, A0, A1, A2, A3);
    ISSUE(6, A0, A1, A2, A3);
    CONSUME(4, B0, B1, B2, B3);
    ISSUE(7, B0, B1, B2, B3);
    CONSUME(5, C0, C1, C2, C3);
    CONSUME(6, A0, A1, A2, A3);
    CONSUME(7, B0, B1, B2, B3);

#undef ISSUE
#undef PROC
#undef CONSUME

    // peel/tail pickup: <=4 scalar elements per row, fully parallel
    if (tid < RPB * 8) {
        int r = tid >> 3, e = tid & 7;
        int row = r0 + r;
        int s = (4 - (row & 3)) & 3;
        int nb = (NCOLS - s) >> 2;
        int done = s + 4 * nb;
        int col = -1;
        if (e < s) col = e;
        else if (e - s < NCOLS - done) col = done + (e - s);
        if (col >= 0) {
            float m = ms[(size_t)row * LD + col];
            if (m > FCUT_LOG) push(r, col, m);
        }
    }
    __syncthreads();

    // epilogue: exact binning + candidate emission from LDS pairs
    for (int r = 0; r < RPB; ++r) {
        int row = r0 + r;
        unsigned C = cnt[r];
        unsigned Cc = (C < CAP) ? C : CAP;
        float rr = refs[row];
        for (unsigned i = tid; i < Cc; i += 256) {
            uint2 pr = pairs[r * CAP + i];
            int col = (int)pr.x;
            float m = __uint_as_float(pr.y);
            float v = inner_val(m, rr, srcs[col]);
            int g = (int)floorf((0.5f - v) * 100.0f) + 1;   // guess
            g = (g < 0) ? 0 : ((g > NBINS) ? NBINS : g);
            while (g < NBINS && t[g] >= v) ++g;             // verify (<=1 step)
            while (g > 0 && t[g - 1] < v) --g;
            atomicAdd(&sub[g], 1u);
            if (use_cand) {
                cand_col[(size_t)row * CAP + i] = (unsigned)col;
                cand_v[(size_t)row * CAP + i]   = v;
            }
        }
        if (tid == 0) {
            if (use_cand) candcnt[row] = C;
            if (C > CAP) atomicOr(ovfl, 1u);   // bins unreliable -> full fallback
        }
    }
    __syncthreads();

    if (tid < 64) {   // block-level hist -> global; fast+overflow mass -> bin 63
        unsigned v = sub[tid];
        unsigned p = v;
        #pragma unroll
        for (int off = 1; off < 64; off <<= 1) {
            unsigned u = __shfl_up(p, off);
            if (tid >= off) p += u;
        }
        unsigned binned = __shfl(p, 63);
        unsigned g = (tid == 63) ? (v + (unsigned)(RPB * NCOLS) - binned) : v;
        if (g) atomicAdd(&hist[tid], g);
    }
}

// Per-row count. Fast path (candidates valid): one wave per row over <=CAP
// candidate values. Fallback (grid-uniform predicate): 256-thread full scan
// of 4 rows. Threshold recomputed per-wave from hist (mid_kernel removed).
__global__ __launch_bounds__(256) void count_kernel(
    const float* __restrict__ ms, const float* __restrict__ refs,
    const float* __restrict__ srcs, const unsigned* __restrict__ hist,
    const unsigned* __restrict__ ovfl, const unsigned* __restrict__ candcnt,
    const float* __restrict__ cand_v, unsigned* __restrict__ rowcnt,
    int use_cand)
{
    __shared__ unsigned tot;
    float th; int ns;
    wave_thres(hist, &th, &ns);
    bool fast = (use_cand && ns <= 41 && *ovfl == 0u);   // grid-uniform

    if (fast) {
        int tid = threadIdx.x, wv = tid >> 6, lane = tid & 63;
        int row = blockIdx.x * 4 + wv;
        unsigned C = candcnt[row];
        unsigned c = 0;
        if (C <= CAP) {
            const float* cv = cand_v + (size_t)row * CAP;
            for (unsigned i = lane; i < C; i += 64)
                c += (cv[i] > th) ? 1u : 0u;
        } else {   // bucket overflow (practically never): full row scan
            float rr = refs[row];
            const float* mrow = ms + (size_t)row * LD;
            for (int col = lane; col < NCOLS; col += 64)
                c += (inner_val(mrow[col], rr, srcs[col]) > th) ? 1u : 0u;
        }
        #pragma unroll
        for (int off = 32; off > 0; off >>= 1) c += __shfl_down(c, off);
        if (lane == 0) rowcnt[row] = c;
        return;
    }

    // full recount fallback (runs only when the candidate path is invalid)
    for (int r4 = 0; r4 < 4; ++r4) {
        int row = blockIdx.x * 4 + r4;
        if (threadIdx.x == 0) tot = 0;
        __syncthreads();
        float rr = refs[row];
        const float* mrow = ms + (size_t)row * LD;
        unsigned c = 0;
        for (int col = threadIdx.x; col < NCOLS; col += 256)
            c += (inner_val(mrow[col], rr, srcs[col]) > th) ? 1u : 0u;
        atomicAdd(&tot, c);
        __syncthreads();
        if (threadIdx.x == 0) rowcnt[row] = tot;
        __syncthreads();
    }
}

// Exclusive prefix over 8192 row counts (single block; always runs).
// 2-barrier version: wave-shuffle scan + one 16-partial pass (was 20
// __syncthreads across a 10-step Hillis-Steele loop).
__global__ __launch_bounds__(1024) void scan_kernel(
    const unsigned* __restrict__ rowcnt, unsigned* __restrict__ rowoff)
{
    __shared__ unsigned wsum[16];
    int tid = threadIdx.x, lane = tid & 63, wv = tid >> 6;
    int r0 = tid * 8;
    unsigned c[8], s = 0;
    #pragma unroll
    for (int k = 0; k < 8; ++k) { c[k] = rowcnt[r0 + k]; s += c[k]; }
    unsigned p = s;                       // inclusive scan of s within wave
    #pragma unroll
    for (int off = 1; off < 64; off <<= 1) {
        unsigned u = __shfl_up(p, off);
        if (lane >= off) p += u;
    }
    if (lane == 63) wsum[wv] = p;         // wave totals
    __syncthreads();
    if (wv == 0 && lane < 16) {           // inclusive scan of 16 wave totals
        unsigned w = wsum[lane];
        #pragma unroll
        for (int off = 1; off < 16; off <<= 1) {
            unsigned u = __shfl_up(w, off);
            if (lane >= off) w += u;
        }
        wsum[lane] = w;
    }
    __syncthreads();
    unsigned excl = (wv > 0 ? wsum[wv - 1] : 0u) + (p - s);  // thread-exclusive
    #pragma unroll
    for (int k = 0; k < 8; ++k) { rowoff[r0 + k] = excl; excl += c[k]; }
    if (tid == 1023) rowoff[NROWS] = excl;
}

// One wave per row; candidate path touches NO matrix data: filter <=CAP
// candidates by v>th, rank survivors by col (exact row-major order), write.
// Full-scan fallback per row when candidates are unusable.
// Threshold recomputed per-wave from hist (mid_kernel removed).
__global__ __launch_bounds__(256) void cwrite_kernel(
    const float* __restrict__ ms, const float* __restrict__ refs,
    const float* __restrict__ srcs, const unsigned* __restrict__ hist,
    const unsigned* __restrict__ ovfl, const unsigned* __restrict__ rowoff,
    const unsigned* __restrict__ candcnt, const unsigned* __restrict__ cand_col,
    const float* __restrict__ cand_v, float* __restrict__ out, int use_cand)
{
    __shared__ unsigned s_col[4][64];
    __shared__ float    s_val[4][64];
    int tid = threadIdx.x, wv = tid >> 6, lane = tid & 63;
    int row = blockIdx.x * 4 + wv;
    unsigned base = rowoff[row], next = rowoff[row + 1];
    if (base == next || base >= MAXC) return;   // wave-uniform exit
    float th; int ns;
    wave_thres(hist, &th, &ns);
    unsigned k = next - base;
    bool full = (!use_cand) || (ns >= 42) || (*ovfl != 0u) ||
                (candcnt[row] > CAP) || (k > 64);

    if (!full) {
        unsigned C = candcnt[row];
        const unsigned* cc = cand_col + (size_t)row * CAP;
        const float*    cv = cand_v  + (size_t)row * CAP;
        unsigned nrun = 0;
        for (unsigned c0 = 0; c0 < C; c0 += 64) {
            unsigned i = c0 + lane;
            bool sel = false; unsigned col = 0; float v = 0.f;
            if (i < C) { col = cc[i]; v = cv[i]; sel = (v > th); }
            unsigned long long mk = __ballot(sel);
            if (sel) {
                unsigned idx = nrun + (unsigned)__popcll(mk & ((1ull << lane) - 1ull));
                if (idx < 64) { s_col[wv][idx] = col; s_val[wv][idx] = v; }
            }
            nrun += (unsigned)__popcll(mk);
        }
        __builtin_amdgcn_s_waitcnt(0);       // drain LDS writes
        __builtin_amdgcn_wave_barrier();     // block compiler reordering
        unsigned kk = (nrun < k) ? nrun : k;
        if (kk > 64) kk = 64;
        if (lane < (int)kk) {
            unsigned mycol = s_col[wv][lane];
            float    myval = s_val[wv][lane];
            unsigned rank = 0;
            for (unsigned j = 0; j < kk; ++j)
                rank += (s_col[wv][j] < mycol) ? 1u : 0u;
            unsigned pos = base + rank;
            if (pos < MAXC) {
                out[pos]            = (float)row;
                out[MAXC + pos]     = (float)mycol;
                out[2 * MAXC + pos] = myval;
            }
        }
        return;
    }

    // full-row ordered ballot scan (cold path; correct for any input)
    float rr = refs[row];
    const float* mrow = ms + (size_t)row * LD;
    unsigned running = base;
    for (int c0 = 0; c0 < NCOLS && running < next && running < MAXC; c0 += 64) {
        int col = c0 + lane;
        float v = inner_val(mrow[col], rr, srcs[col]);
        bool pred = v > th;
        unsigned long long mk = __ballot(pred);
        if (pred) {
            unsigned pos = running + (unsigned)__popcll(mk & ((1ull << lane) - 1ull));
            if (pos < MAXC) {
                out[pos]            = (float)row;
                out[MAXC + pos]     = (float)col;
                out[2 * MAXC + pos] = v;
            }
        }
        running += (unsigned)__popcll(mk);
    }
}

extern "C" void kernel_launch(void* const* d_in, const int* in_sizes, int n_in,
                              void* d_out, int out_size, void* d_ws, size_t ws_size,
                              hipStream_t stream) {
    const float* ms  = (const float*)d_in[0];  // 8193x8193
    const float* ref = (const float*)d_in[1];  // 8192
    const float* src = (const float*)d_in[2];  // 8192
    float* out = (float*)d_out;                // [refIdx | srcIdx | scores] as f32

    char* w = (char*)d_ws;
    unsigned* hist   = (unsigned*)(w);                    // 64 u32
    unsigned* ovfl   = (unsigned*)(w + 264);
    unsigned* rowcnt = (unsigned*)(w + 512);              // 8192 u32
    unsigned* rowoff = (unsigned*)(w + 512 + NROWS * 4);  // 8193 u32
    size_t cc_off = 512 + (size_t)NROWS * 4 + (size_t)(NROWS + 1) * 4;
    cc_off = (cc_off + 255) & ~(size_t)255;
    unsigned* candcnt  = (unsigned*)(w + cc_off);         // 8192 u32
    size_t col_off = cc_off + (size_t)NROWS * 4;
    unsigned* cand_col = (unsigned*)(w + col_off);        // 8192*CAP u32
    size_t cv_off = col_off + (size_t)NROWS * CAP * 4;
    float* cand_v      = (float*)(w + cv_off);            // 8192*CAP f32
    size_t end_off = cv_off + (size_t)NROWS * CAP * 4;    // ~12.7 MB total

    int use_cand = (ws_size >= end_off) ? 1 : 0;

    init_kernel<<<96, 256, 0, stream>>>(out, hist, ovfl);
    hist_kernel<<<NROWS / RPB, 256, 0, stream>>>(ms, ref, src, hist, candcnt,
                                                 cand_col, cand_v, ovfl, use_cand);
    count_kernel<<<NROWS / 4, 256, 0, stream>>>(ms, ref, src, hist, ovfl,
                                                candcnt, cand_v, rowcnt, use_cand);
    scan_kernel<<<1, 1024, 0, stream>>>(rowcnt, rowoff);
    cwrite_kernel<<<NROWS / 4, 256, 0, stream>>>(ms, ref, src, hist, ovfl,
                                                 rowoff, candcnt, cand_col,
                                                 cand_v, out, use_cand);
}